// Round 7
// baseline (881.128 us; speedup 1.0000x reference)
//
#include <hip/hip_runtime.h>
#include <cstdint>
#include <cstddef>

typedef unsigned long long u64;

// ---------------- prep 1: W2 transpose (f32, + zero row 256) + folded output weights ----------------
__global__ void prep_weights(const float* __restrict__ W2, const float* __restrict__ Wc2,
                             const float* __restrict__ bc2, const float* __restrict__ WA,
                             float* __restrict__ Wt2f, double* __restrict__ wEff,
                             double* __restrict__ bEff)
{
  int id = blockIdx.x * 256 + (int)threadIdx.x;
  if (id < 65536){ int i = id >> 8, j = id & 255; Wt2f[(i<<8)+j] = W2[j*256+i]; }  // Wt2f[i][j] = W2[j][i]
  else if (id < 65792){ Wt2f[id] = 0.0f; }                                          // zero row (idx 256)
  if (id < 32){ double s = 0.0; for (int c=0;c<64;c++) s += (double)WA[c]*(double)Wc2[c*32+id]; wEff[id] = s; }
  if (id == 32){ double s = 0.0; for (int c=0;c<64;c++) s += (double)WA[c]*(double)bc2[c]; *bEff = s; }
}

// ---------------- prep 2: rate-encode probabilities (f64) ----------------
__global__ void prep_probs(const float* __restrict__ x, double* __restrict__ probs, int B)
{
  int b = blockIdx.x, k = (int)threadIdx.x;
  if (b >= B || k >= 24) return;
  double* pb = probs + (size_t)b*24;
  if (k >= 18){ pb[k] = -1.0; return; }
  int fk, g0, gn;
  if (k < 12){ fk = k;          g0 = 0;  gn = 12; }
  else if (k < 15){ fk = 6+(k-12);  g0 = 6;  gn = 6; }
  else           { fk = 12+(k-15); g0 = 12; gn = 6; }
  const float* xb = x + (size_t)b*18;
  double mn = (double)xb[g0], mx = mn;
  for (int f = 1; f < gn; f++){ double v = (double)xb[g0+f]; mn = fmin(mn, v); mx = fmax(mx, v); }
  double rng = mx - mn; if (rng == 0.0) rng = 1.0;
  double norm = ((double)xb[fk] - mn) / rng;
  double p = (100.0 * norm) * 0.001;
  p = fmin(fmax(p, 0.0), 1.0);
  pb[k] = p;
}

// ---------------- prep 3: pack spike bits, TRANSPOSED to (b, t), t-padded with 2 zeros ----------------
__global__ void prep_enc(const float* __restrict__ u1, const float* __restrict__ u2,
                         const float* __restrict__ u3, const double* __restrict__ probs,
                         unsigned* __restrict__ encT, int B, int T)
{
  int b = blockIdx.x * blockDim.x + (int)threadIdx.x;
  int t = blockIdx.y;
  if (b >= B) return;
  if (t >= T){ encT[(size_t)b*(T+2) + t] = 0u; return; }
  const double* pb = probs + (size_t)b*24;
  size_t r = (size_t)t * B + b;
  const float* a1 = u1 + r*12;
  const float* a2 = u2 + r*6;
  const float* a3 = u3 + r*6;
  unsigned e = 0;
  #pragma unroll
  for (int k = 0; k < 12; k++) if ((double)a1[k] < pb[k])    e |= (1u << k);
  #pragma unroll
  for (int h = 0; h < 3; h++)  if ((double)a2[h] < pb[12+h]) e |= (1u << (12+h));
  #pragma unroll
  for (int h = 0; h < 3; h++)  if ((double)a3[h] < pb[15+h]) e |= (1u << (15+h));
  encT[(size_t)b*(T+2) + t] = e;
}

// ---------------- main: 1024-thread blocks (16 waves), 2 batch rows per wave ----------------
// R6: half of W2 (rows 0..127, 128KB) staged in pooled LDS -> L2 gather traffic halved
// (was ~32 TB/s ~ the 34.5 TB/s L2 ceiling). Ballot masks split low32/high32 = LDS/global.
// 1 block/CU (LDS-capped), 4 waves/SIMD, no persistent spike bools (resets recomputed).
__global__ __launch_bounds__(1024, 4) void snn_main(
    const unsigned* __restrict__ encT,
    const float* __restrict__ b1, const float* __restrict__ b2, const float* __restrict__ b3,
    const float* __restrict__ W1, const float* __restrict__ W3,
    const float* __restrict__ Wc1, const float* __restrict__ bc1,
    const float* __restrict__ Wt2f,
    const double* __restrict__ wEff, const double* __restrict__ bEff,
    float* __restrict__ out, int B, int T)
{
  __shared__ __align__(16) float s_w2[129*256];  // rows 0..127 of Wt2f + zero row 128 (132096 B)
  __shared__ __align__(16) float s_w1[13*256];   // s_w1[k][j] = W1[j][k], row 12 = 0 (13312 B)
  __shared__ __align__(16) float s_w3[257*4];    // s_w3[i][c] = W3[c][i] (c<3), col3+row256 = 0 (4112 B)

  const int tid  = (int)threadIdx.x;
  const int lane = tid & 63;
  const int wv   = tid >> 6;           // 0..15
  const int l4   = lane << 2;
  const int lcl  = (lane < 3) ? lane : 3;

  // ---- stage LDS ----
  {
    const float4* src = (const float4*)Wt2f;
    float4* dst = (float4*)s_w2;
    #pragma unroll
    for (int i = 0; i < 8; i++) dst[tid + (i << 10)] = src[tid + (i << 10)];
    if (tid < 64) dst[8192 + tid] = make_float4(0.f, 0.f, 0.f, 0.f);   // zero row 128
  }
  for (int i = tid; i < 13*256; i += 1024){
    int k = i >> 8, j = i & 255;
    s_w1[i] = (k < 12) ? W1[j*12 + k] : 0.f;
  }
  for (int i = tid; i < 1028; i += 1024){
    int r = i >> 2, c = i & 3;
    s_w3[i] = (r < 256 && c < 3) ? W3[c*256 + r] : 0.f;
  }
  __syncthreads();

  const int r0 = blockIdx.x * 32 + wv * 2;   // this wave's two batch rows: r0, r0+1

  const float4 b1f = *(const float4*)(b1 + l4);
  const float4 b2f = *(const float4*)(b2 + l4);
  const double b1d0=b1f.x, b1d1=b1f.y, b1d2=b1f.z, b1d3=b1f.w;
  const double b2d0=b2f.x, b2d1=b2f.y, b2d2=b2f.z, b2d3=b2f.w;
  const float  b3f = (lane < 3) ? b3[lane] : 0.f;
  double wc1b=0.0, pre0=0.0, pre1=0.0, pre2=0.0, pre3=0.0;
  if (lane < 32){
    double wa = (double)Wc1[lane*3+0];
    wc1b      = (double)Wc1[lane*3+1];
    double wc = (double)Wc1[lane*3+2];
    double bd = (double)bc1[lane];
    pre0 = bd;            // td=0, td2=0
    pre1 = bd + wa;       // td=1, td2=0
    pre2 = bd + wc;       // td=0, td2=1
    pre3 = bd + wa + wc;  // td=1, td2=1
  }

  double m1[2][4] = {}, m2[2][4] = {}, m3[2] = {}, m4[2][3] = {};

  const unsigned* ebp[2];
  ebp[0] = encT + (size_t)((r0     < B) ? r0     : 0) * (T + 2);
  ebp[1] = encT + (size_t)((r0 + 1 < B) ? r0 + 1 : 0) * (T + 2);
  unsigned ecur[2], enx[2];
  #pragma unroll
  for (int rr = 0; rr < 2; rr++){
    ecur[rr] = __builtin_amdgcn_readfirstlane(ebp[rr][0]);
    enx[rr]  = __builtin_amdgcn_readfirstlane(ebp[rr][1]);
  }

  for (int t = 0; t < T; t++){
    #pragma unroll
    for (int rr = 0; rr < 2; rr++){
      // ---- layer 1: reset recomputed from membrane, gather from LDS (4-wide, zero row 12) ----
      double a0 = ((m1[rr][0] > 1.0) ? -1.0 : 0.0) + b1d0;
      double a1 = ((m1[rr][1] > 1.0) ? -1.0 : 0.0) + b1d1;
      double a2 = ((m1[rr][2] > 1.0) ? -1.0 : 0.0) + b1d2;
      double a3 = ((m1[rr][3] > 1.0) ? -1.0 : 0.0) + b1d3;
      {
        unsigned w = ecur[rr] & 0xFFFu;
        while (w){
          int k0 = __builtin_ctz(w); w &= w-1;
          int k1 = 12, k2 = 12, k3 = 12;
          if (w){ k1 = __builtin_ctz(w); w &= w-1;
            if (w){ k2 = __builtin_ctz(w); w &= w-1;
              if (w){ k3 = __builtin_ctz(w); w &= w-1; } } }
          const float4 qa = *(const float4*)&s_w1[(k0<<8)+l4];
          const float4 qb = *(const float4*)&s_w1[(k1<<8)+l4];
          const float4 qc = *(const float4*)&s_w1[(k2<<8)+l4];
          const float4 qd = *(const float4*)&s_w1[(k3<<8)+l4];
          a0 += (double)qa.x; a1 += (double)qa.y; a2 += (double)qa.z; a3 += (double)qa.w;
          a0 += (double)qb.x; a1 += (double)qb.y; a2 += (double)qb.z; a3 += (double)qb.w;
          a0 += (double)qc.x; a1 += (double)qc.y; a2 += (double)qc.z; a3 += (double)qc.w;
          a0 += (double)qd.x; a1 += (double)qd.y; a2 += (double)qd.z; a3 += (double)qd.w;
        }
      }
      m1[rr][0] = fma(0.9, m1[rr][0], a0);
      m1[rr][1] = fma(0.9, m1[rr][1], a1);
      m1[rr][2] = fma(0.9, m1[rr][2], a2);
      m1[rr][3] = fma(0.9, m1[rr][3], a3);
      u64 w0 = __ballot(m1[rr][0] > 1.0);
      u64 w1 = __ballot(m1[rr][1] > 1.0);
      u64 w2 = __ballot(m1[rr][2] > 1.0);
      u64 w3m = __ballot(m1[rr][3] > 1.0);
      u64 wl0 = w0 & 0xFFFFFFFFull, wg0 = w0 >> 32;
      u64 wl1 = w1 & 0xFFFFFFFFull, wg1 = w1 >> 32;
      u64 wl2 = w2 & 0xFFFFFFFFull, wg2 = w2 >> 32;
      u64 wl3 = w3m & 0xFFFFFFFFull, wg3 = w3m >> 32;

      // ---- layer 2, global batch-1: issue loads early (zero row 256 when empty) ----
      int i0 = wg0 ? (((int)__builtin_ctzll(wg0)<<2)|0)+128 : 256;  wg0 &= wg0-1;
      int i1 = wg1 ? (((int)__builtin_ctzll(wg1)<<2)|1)+128 : 256;  wg1 &= wg1-1;
      int i2 = wg2 ? (((int)__builtin_ctzll(wg2)<<2)|2)+128 : 256;  wg2 &= wg2-1;
      int i3 = wg3 ? (((int)__builtin_ctzll(wg3)<<2)|3)+128 : 256;  wg3 &= wg3-1;
      const float4 g0 = *(const float4*)(Wt2f + ((size_t)i0<<8) + l4);
      const float4 g1 = *(const float4*)(Wt2f + ((size_t)i1<<8) + l4);
      const float4 g2 = *(const float4*)(Wt2f + ((size_t)i2<<8) + l4);
      const float4 g3 = *(const float4*)(Wt2f + ((size_t)i3<<8) + l4);

      const unsigned e2 = ebp[rr][t+2];   // enc prefetch (L1-hot)

      // ---- layer-2 accum init (reset recomputed) + LDS-half gather (overlaps g latency) ----
      double c0 = ((m2[rr][0] > 1.0) ? -1.0 : 0.0) + b2d0;
      double c1 = ((m2[rr][1] > 1.0) ? -1.0 : 0.0) + b2d1;
      double c2 = ((m2[rr][2] > 1.0) ? -1.0 : 0.0) + b2d2;
      double c3 = ((m2[rr][3] > 1.0) ? -1.0 : 0.0) + b2d3;
      while (wl0 | wl1 | wl2 | wl3){
        int j0 = wl0 ? (((int)__builtin_ctzll(wl0)<<2)|0) : 128;  wl0 &= wl0-1;
        int j1 = wl1 ? (((int)__builtin_ctzll(wl1)<<2)|1) : 128;  wl1 &= wl1-1;
        int j2 = wl2 ? (((int)__builtin_ctzll(wl2)<<2)|2) : 128;  wl2 &= wl2-1;
        int j3 = wl3 ? (((int)__builtin_ctzll(wl3)<<2)|3) : 128;  wl3 &= wl3-1;
        const float4 q0 = *(const float4*)&s_w2[(j0<<8)+l4];
        const float4 q1 = *(const float4*)&s_w2[(j1<<8)+l4];
        const float4 q2 = *(const float4*)&s_w2[(j2<<8)+l4];
        const float4 q3 = *(const float4*)&s_w2[(j3<<8)+l4];
        c0 += (double)q0.x; c1 += (double)q0.y; c2 += (double)q0.z; c3 += (double)q0.w;
        c0 += (double)q1.x; c1 += (double)q1.y; c2 += (double)q1.z; c3 += (double)q1.w;
        c0 += (double)q2.x; c1 += (double)q2.y; c2 += (double)q2.z; c3 += (double)q2.w;
        c0 += (double)q3.x; c1 += (double)q3.y; c2 += (double)q3.z; c3 += (double)q3.w;
      }
      // ---- consume global batch-1 ----
      c0 += (double)g0.x; c1 += (double)g0.y; c2 += (double)g0.z; c3 += (double)g0.w;
      c0 += (double)g1.x; c1 += (double)g1.y; c2 += (double)g1.z; c3 += (double)g1.w;
      c0 += (double)g2.x; c1 += (double)g2.y; c2 += (double)g2.z; c3 += (double)g2.w;
      c0 += (double)g3.x; c1 += (double)g3.y; c2 += (double)g3.z; c3 += (double)g3.w;
      // ---- remaining global batches ----
      while (wg0 | wg1 | wg2 | wg3){
        int j0 = wg0 ? (((int)__builtin_ctzll(wg0)<<2)|0)+128 : 256;  wg0 &= wg0-1;
        int j1 = wg1 ? (((int)__builtin_ctzll(wg1)<<2)|1)+128 : 256;  wg1 &= wg1-1;
        int j2 = wg2 ? (((int)__builtin_ctzll(wg2)<<2)|2)+128 : 256;  wg2 &= wg2-1;
        int j3 = wg3 ? (((int)__builtin_ctzll(wg3)<<2)|3)+128 : 256;  wg3 &= wg3-1;
        const float4 h0 = *(const float4*)(Wt2f + ((size_t)j0<<8) + l4);
        const float4 h1 = *(const float4*)(Wt2f + ((size_t)j1<<8) + l4);
        const float4 h2 = *(const float4*)(Wt2f + ((size_t)j2<<8) + l4);
        const float4 h3 = *(const float4*)(Wt2f + ((size_t)j3<<8) + l4);
        c0 += (double)h0.x; c1 += (double)h0.y; c2 += (double)h0.z; c3 += (double)h0.w;
        c0 += (double)h1.x; c1 += (double)h1.y; c2 += (double)h1.z; c3 += (double)h1.w;
        c0 += (double)h2.x; c1 += (double)h2.y; c2 += (double)h2.z; c3 += (double)h2.w;
        c0 += (double)h3.x; c1 += (double)h3.y; c2 += (double)h3.z; c3 += (double)h3.w;
      }
      m2[rr][0] = fma(0.9, m2[rr][0], c0);
      m2[rr][1] = fma(0.9, m2[rr][1], c1);
      m2[rr][2] = fma(0.9, m2[rr][2], c2);
      m2[rr][3] = fma(0.9, m2[rr][3], c3);
      u64 v0 = __ballot(m2[rr][0] > 1.0);
      u64 v1 = __ballot(m2[rr][1] > 1.0);
      u64 v2 = __ballot(m2[rr][2] > 1.0);
      u64 v3 = __ballot(m2[rr][3] > 1.0);

      // ---- layer 3 from LDS (4-wide, zero row 256) ----
      double cl3 = ((m3[rr] > 1.0) ? -1.0 : 0.0) + (double)b3f;
      while (v0 | v1 | v2 | v3){
        int j0 = v0 ? (((int)__builtin_ctzll(v0)<<2)|0) : 256;  v0 &= v0-1;
        int j1 = v1 ? (((int)__builtin_ctzll(v1)<<2)|1) : 256;  v1 &= v1-1;
        int j2 = v2 ? (((int)__builtin_ctzll(v2)<<2)|2) : 256;  v2 &= v2-1;
        int j3 = v3 ? (((int)__builtin_ctzll(v3)<<2)|3) : 256;  v3 &= v3-1;
        cl3 += (double)s_w3[(j0<<2) + lcl];
        cl3 += (double)s_w3[(j1<<2) + lcl];
        cl3 += (double)s_w3[(j2<<2) + lcl];
        cl3 += (double)s_w3[(j3<<2) + lcl];
      }
      m3[rr] = fma(0.9, m3[rr], cl3);
      const unsigned s3 = (unsigned)(__ballot((lane < 3) && (m3[rr] > 1.0)) & 7ull);

      // ---- layer 4 (conv1 LIF): lane<32 = out-channel o, h = 0..2 ----
      const unsigned td  = (ecur[rr] >> 12) & 7u;
      const unsigned td2 = (ecur[rr] >> 15) & 7u;
      {
        double cur, t1v, t2v;
        t1v = (td2 & 1u) ? pre2 : pre0;  t2v = (td2 & 1u) ? pre3 : pre1;
        cur = (td & 1u) ? t2v : t1v;
        if (s3 & 1u) cur += wc1b;
        cur += (m4[rr][0] > 1.0) ? -1.0 : 0.0;
        m4[rr][0] = fma(0.9, m4[rr][0], cur);
        t1v = (td2 & 2u) ? pre2 : pre0;  t2v = (td2 & 2u) ? pre3 : pre1;
        cur = (td & 2u) ? t2v : t1v;
        if (s3 & 2u) cur += wc1b;
        cur += (m4[rr][1] > 1.0) ? -1.0 : 0.0;
        m4[rr][1] = fma(0.9, m4[rr][1], cur);
        t1v = (td2 & 4u) ? pre2 : pre0;  t2v = (td2 & 4u) ? pre3 : pre1;
        cur = (td & 4u) ? t2v : t1v;
        if (s3 & 4u) cur += wc1b;
        cur += (m4[rr][2] > 1.0) ? -1.0 : 0.0;
        m4[rr][2] = fma(0.9, m4[rr][2], cur);
      }

      // ---- rotate enc pipeline ----
      ecur[rr] = enx[rr];
      enx[rr]  = __builtin_amdgcn_readfirstlane(e2);
    }
  }

  // ---- output: out[b,m] = bEff + sum_o spk4_final[o,m] * wEff[o] ----
  const double wEd = (lane < 32) ? wEff[lane] : 0.0;
  const double be = *bEff;
  #pragma unroll
  for (int rr = 0; rr < 2; rr++){
    double o0 = ((lane < 32) && (m4[rr][0] > 1.0)) ? wEd : 0.0;
    double o1 = ((lane < 32) && (m4[rr][1] > 1.0)) ? wEd : 0.0;
    double o2 = ((lane < 32) && (m4[rr][2] > 1.0)) ? wEd : 0.0;
    for (int off = 32; off > 0; off >>= 1){
      o0 += __shfl_xor(o0, off, 64);
      o1 += __shfl_xor(o1, off, 64);
      o2 += __shfl_xor(o2, off, 64);
    }
    if (lane == 0 && (r0 + rr) < B){
      out[(r0+rr)*3+0] = (float)(o0 + be);
      out[(r0+rr)*3+1] = (float)(o1 + be);
      out[(r0+rr)*3+2] = (float)(o2 + be);
    }
  }
}

// ---------------- host ----------------
extern "C" void kernel_launch(void* const* d_in, const int* in_sizes, int n_in,
                              void* d_out, int out_size, void* d_ws, size_t ws_size,
                              hipStream_t stream)
{
  const float* x   = (const float*)d_in[0];
  const float* u1  = (const float*)d_in[1];
  const float* u2  = (const float*)d_in[2];
  const float* u3  = (const float*)d_in[3];
  const float* W1  = (const float*)d_in[4];
  const float* b1  = (const float*)d_in[5];
  const float* W2  = (const float*)d_in[6];
  const float* b2  = (const float*)d_in[7];
  const float* W3  = (const float*)d_in[8];
  const float* b3  = (const float*)d_in[9];
  const float* Wc1 = (const float*)d_in[10];
  const float* bc1 = (const float*)d_in[11];
  const float* Wc2 = (const float*)d_in[12];
  const float* bc2 = (const float*)d_in[13];
  const float* WA  = (const float*)d_in[14];
  float* out = (float*)d_out;

  const int B = in_sizes[0] / 18;
  const int T = in_sizes[1] / (B * 12);

  char* ws = (char*)d_ws;
  float*  Wt2f  = (float*)(ws + 0);                        // 257*256*4 = 263168
  double* wEff  = (double*)(ws + 263168);                  // 256
  double* bEff  = (double*)(ws + 263424);                  // 8
  double* probs = (double*)(ws + 263432);                  // B*24*8
  unsigned* encT= (unsigned*)(ws + 263432 + (size_t)B*24*8); // B*(T+2)*4

  hipLaunchKernelGGL(prep_weights, dim3(257), dim3(256), 0, stream,
                     W2, Wc2, bc2, WA, Wt2f, wEff, bEff);
  hipLaunchKernelGGL(prep_probs, dim3(B), dim3(64), 0, stream, x, probs, B);
  hipLaunchKernelGGL(prep_enc, dim3((B+255)/256, T+2), dim3(256), 0, stream,
                     u1, u2, u3, probs, encT, B, T);
  hipLaunchKernelGGL(snn_main, dim3((B+31)/32), dim3(1024), 0, stream,
                     encT, b1, b2, b3, W1, W3, Wc1, bc1, Wt2f, wEff, bEff, out, B, T);
}